// Round 1
// 550.498 us; speedup vs baseline: 1.0784x; 1.0784x over previous
//
#include <hip/hip_runtime.h>
#include <hip/hip_bf16.h>

// ---------- types ----------
typedef __attribute__((ext_vector_type(8))) short   sv8;    // 8 bf16 payloads
typedef __attribute__((ext_vector_type(8))) __bf16  bfv8;
typedef __attribute__((ext_vector_type(4))) float   f32x4;

// fp32 -> bf16 round-to-nearest-even (bit trick)
__device__ __forceinline__ short f2bf(float f) {
  union { float f; unsigned u; } v; v.f = f;
  unsigned r = v.u + 0x7fffu + ((v.u >> 16) & 1u);
  return (short)(r >> 16);
}

__device__ __forceinline__ f32x4 mfma16x16x32(sv8 a, sv8 b, f32x4 c) {
  return __builtin_amdgcn_mfma_f32_16x16x32_bf16(
      __builtin_bit_cast(bfv8, a), __builtin_bit_cast(bfv8, b), c, 0, 0, 0);
}

__device__ __forceinline__ float silu(float x) { return x / (1.f + __expf(-x)); }

// ---------- generic bt-GEMM: C[m][n] = sum_k A[m][k]*B[n][k], fp32 in, bf16 MFMA ----------
// Tile 128(M) x 64(N), BK=64, 4 waves (2x2), each wave owns 64x32 (4x2 subtiles).
// Register double-buffer: next K-step's global loads issued right after the first
// barrier, so HBM latency overlaps the MFMA phase.
// blockIdx.z = k-slice (split-K); advances A,B by z*kStride elems, C by z*cSlice elems.
// EPI==1: fused softplus(acc + bias[col])
template<int EPI>
__global__ __launch_bounds__(256) void gemm_bt(
    const float* __restrict__ A, const float* __restrict__ B, float* __restrict__ C,
    const float* __restrict__ bias, int lda, int ldb, int ldc, int kIters,
    int kStride, long cSlice)
{
  __shared__ short As[128 * 72];   // row stride 72 bf16 = 144B (pad kills b128 conflicts)
  __shared__ short Bs[64 * 72];
  const int tid = threadIdx.x;
  A += (long)blockIdx.z * kStride;
  B += (long)blockIdx.z * kStride;
  C += (long)blockIdx.z * cSlice;
  const int rowA0 = blockIdx.y * 128, colB0 = blockIdx.x * 64;
  const int c4 = tid & 15, r0 = tid >> 4;                 // staging coords
  const int wave = tid >> 6, lane = tid & 63;
  const int wm = (wave >> 1) * 64, wn = (wave & 1) * 32;  // 2x2 wave layout
  const int lrow = lane & 15, lq = lane >> 4;
  f32x4 acc[4][2] = {};
  float4 pa[8], pb[4];

  const float* Aptr = &A[(long)(rowA0 + r0) * lda + c4 * 4];
  const float* Bptr = &B[(long)(colB0 + r0) * ldb + c4 * 4];

  // prologue: prefetch K-step 0 into registers
#pragma unroll
  for (int i = 0; i < 8; ++i) pa[i] = *(const float4*)&Aptr[(long)(16 * i) * lda];
#pragma unroll
  for (int i = 0; i < 4; ++i) pb[i] = *(const float4*)&Bptr[(long)(16 * i) * ldb];

  for (int kb = 0; kb < kIters; ++kb) {
    // convert + store current K-step registers to LDS
#pragma unroll
    for (int i = 0; i < 8; ++i) {
      short4 s; s.x = f2bf(pa[i].x); s.y = f2bf(pa[i].y); s.z = f2bf(pa[i].z); s.w = f2bf(pa[i].w);
      *(short4*)&As[(r0 + 16 * i) * 72 + c4 * 4] = s;
    }
#pragma unroll
    for (int i = 0; i < 4; ++i) {
      short4 s; s.x = f2bf(pb[i].x); s.y = f2bf(pb[i].y); s.z = f2bf(pb[i].z); s.w = f2bf(pb[i].w);
      *(short4*)&Bs[(r0 + 16 * i) * 72 + c4 * 4] = s;
    }
    __syncthreads();
    // issue next K-step's global loads NOW — latency hides under the MFMAs below
    if (kb + 1 < kIters) {
      const long ko = (long)(kb + 1) * 64;
#pragma unroll
      for (int i = 0; i < 8; ++i) pa[i] = *(const float4*)&Aptr[(long)(16 * i) * lda + ko];
#pragma unroll
      for (int i = 0; i < 4; ++i) pb[i] = *(const float4*)&Bptr[(long)(16 * i) * ldb + ko];
    }
#pragma unroll
    for (int ks = 0; ks < 2; ++ks) {
      const int kk = ks * 32 + lq * 8;   // A/B operand: [m|n = lane&15][k = quad*8 + j]
      sv8 af[4], bfr[2];
#pragma unroll
      for (int s = 0; s < 4; ++s) af[s] = *(const sv8*)&As[(wm + s * 16 + lrow) * 72 + kk];
#pragma unroll
      for (int s = 0; s < 2; ++s) bfr[s] = *(const sv8*)&Bs[(wn + s * 16 + lrow) * 72 + kk];
#pragma unroll
      for (int sm = 0; sm < 4; ++sm)
#pragma unroll
        for (int sn = 0; sn < 2; ++sn)
          acc[sm][sn] = mfma16x16x32(af[sm], bfr[sn], acc[sm][sn]);
    }
    __syncthreads();
  }
  // C/D layout: col = lane&15, row = quad*4 + reg
#pragma unroll
  for (int sm = 0; sm < 4; ++sm) {
    const int row = rowA0 + wm + sm * 16 + lq * 4;
#pragma unroll
    for (int sn = 0; sn < 2; ++sn) {
      const int col = colB0 + wn + sn * 16 + lrow;
#pragma unroll
      for (int r = 0; r < 4; ++r) {
        float v = acc[sm][sn][r];
        if (EPI == 1) { v += bias[col]; v = (v > 20.f) ? v : log1pf(__expf(v)); }
        C[(long)(row + r) * ldc + col] = v;
      }
    }
  }
}

// ---------- conv step: shift state, dot conv_w, silu ----------
__global__ __launch_bounds__(256) void conv_step(
    const float* __restrict__ xz, const float* __restrict__ cs_in,
    const float* __restrict__ conv_w, const float* __restrict__ conv_b,
    float* __restrict__ cs_out, float* __restrict__ xc)
{
  const long i = (long)blockIdx.x * 256 + threadIdx.x;   // (b*8192 + d), 2M total
  const int b = (int)(i >> 13), d = (int)(i & 8191);
  const float4 c = *(const float4*)&cs_in[i * 4];
  const float4 w = *(const float4*)&conv_w[(long)d * 4];
  const float xi = xz[(long)b * 16384 + d];
  float4 nc; nc.x = c.y; nc.y = c.z; nc.z = c.w; nc.w = xi;
  *(float4*)&cs_out[i * 4] = nc;
  const float v = nc.x * w.x + nc.y * w.y + nc.z * w.z + nc.w * w.w + conv_b[d];
  xc[i] = silu(v);
}

// ---------- zero x_db ----------
__global__ void zero_kernel(float* p) { p[blockIdx.x * 256 + threadIdx.x] = 0.f; }

// ---------- x_db = xc @ W_xproj.T  (M=256, N=160, K=8192), MFMA split-K + atomics ----------
// grid (10 n-tiles, 16 k-slices); block: 4 waves, wave w owns m-subtiles 4w..4w+3
__global__ __launch_bounds__(256) void gemm_xdb(
    const float* __restrict__ xc, const float* __restrict__ W, float* __restrict__ out)
{
  __shared__ short As[256 * 72];
  __shared__ short Bs[16 * 72];
  const int tid = threadIdx.x;
  const int nt = blockIdx.x;
  const long kbase = (long)blockIdx.y * 512;
  const int c4 = tid & 15, r0 = tid >> 4;
  const int wave = tid >> 6, lane = tid & 63;
  const int lrow = lane & 15, lq = lane >> 4;
  f32x4 acc[4] = {};
  for (int kb = 0; kb < 8; ++kb) {
    const long k0 = kbase + kb * 64;
#pragma unroll
    for (int i = 0; i < 16; ++i) {
      const int r = r0 + 16 * i;
      const float4 v = *(const float4*)&xc[(long)r * 8192 + k0 + c4 * 4];
      short4 s; s.x = f2bf(v.x); s.y = f2bf(v.y); s.z = f2bf(v.z); s.w = f2bf(v.w);
      *(short4*)&As[r * 72 + c4 * 4] = s;
    }
    {
      const float4 v = *(const float4*)&W[(long)(nt * 16 + r0) * 8192 + k0 + c4 * 4];
      short4 s; s.x = f2bf(v.x); s.y = f2bf(v.y); s.z = f2bf(v.z); s.w = f2bf(v.w);
      *(short4*)&Bs[r0 * 72 + c4 * 4] = s;
    }
    __syncthreads();
#pragma unroll
    for (int ks = 0; ks < 2; ++ks) {
      const int kk = ks * 32 + lq * 8;
      const sv8 bfr = *(const sv8*)&Bs[lrow * 72 + kk];
#pragma unroll
      for (int s = 0; s < 4; ++s) {
        const sv8 af = *(const sv8*)&As[((wave * 4 + s) * 16 + lrow) * 72 + kk];
        acc[s] = mfma16x16x32(af, bfr, acc[s]);
      }
    }
    __syncthreads();
  }
  const int n = nt * 16 + lrow;
#pragma unroll
  for (int s = 0; s < 4; ++s) {
    const int m0 = (wave * 4 + s) * 16 + lq * 4;
#pragma unroll
    for (int r = 0; r < 4; ++r) atomicAdd(&out[(long)(m0 + r) * 160 + n], acc[s][r]);
  }
}

// ---------- SSM state update + y: 4 lanes per (b,d), each handles 4 of 16 states ----------
__global__ __launch_bounds__(256) void ssm_step(
    const float* __restrict__ ssm_in, const float* __restrict__ x_db,
    const float* __restrict__ dtv, const float* __restrict__ xcw,
    const float* __restrict__ xz, const float* __restrict__ A_log,
    const float* __restrict__ D_param, float* __restrict__ ssm_out, float* __restrict__ y)
{
  const long t = (long)blockIdx.x * 256 + threadIdx.x;   // 8.4M threads
  const long bd = t >> 2; const int sq = (int)(t & 3);
  const int b = (int)(bd >> 13), d = (int)(bd & 8191);
  const float dt = dtv[bd];
  const float xc = xcw[bd];
  const float4 al = *(const float4*)&A_log[(long)d * 16 + sq * 4];
  const float4 st = *(const float4*)&ssm_in[bd * 16 + sq * 4];
  const float4 Bv = *(const float4*)&x_db[(long)b * 160 + 128 + sq * 4];
  const float4 Cv = *(const float4*)&x_db[(long)b * 160 + 144 + sq * 4];
  const float xdt = xc * dt;
  float4 ns;
  ns.x = st.x * __expf(dt * -__expf(al.x)) + xdt * Bv.x;
  ns.y = st.y * __expf(dt * -__expf(al.y)) + xdt * Bv.y;
  ns.z = st.z * __expf(dt * -__expf(al.z)) + xdt * Bv.z;
  ns.w = st.w * __expf(dt * -__expf(al.w)) + xdt * Bv.w;
  *(float4*)&ssm_out[bd * 16 + sq * 4] = ns;
  float part = ns.x * Cv.x + ns.y * Cv.y + ns.z * Cv.z + ns.w * Cv.w;
  part += __shfl_xor(part, 1);
  part += __shfl_xor(part, 2);
  if (sq == 0) {
    const float z = xz[(long)b * 16384 + 8192 + d];
    float yv = part + D_param[d] * xc;
    y[bd] = yv * silu(z);
  }
}

// ---------- reduce 8 split-K partials into out ----------
__global__ __launch_bounds__(256) void reduce8(const float* __restrict__ p, float* __restrict__ out)
{
  const long i = (long)blockIdx.x * 256 + threadIdx.x;   // 131072 float4s
  float4 s = {0.f, 0.f, 0.f, 0.f};
#pragma unroll
  for (int j = 0; j < 8; ++j) {
    const float4 v = *(const float4*)&p[(long)j * 524288 + i * 4];
    s.x += v.x; s.y += v.y; s.z += v.z; s.w += v.w;
  }
  *(float4*)&out[i * 4] = s;
}

extern "C" void kernel_launch(void* const* d_in, const int* in_sizes, int n_in,
                              void* d_out, int out_size, void* d_ws, size_t ws_size,
                              hipStream_t stream) {
  const float* x        = (const float*)d_in[0];
  const float* conv_in  = (const float*)d_in[1];
  const float* ssm_in   = (const float*)d_in[2];
  const float* W_in     = (const float*)d_in[3];
  const float* conv_w   = (const float*)d_in[4];
  const float* conv_b   = (const float*)d_in[5];
  const float* W_xproj  = (const float*)d_in[6];
  const float* W_dt     = (const float*)d_in[7];
  const float* b_dt     = (const float*)d_in[8];
  const float* A_log    = (const float*)d_in[9];
  const float* D_param  = (const float*)d_in[10];
  const float* W_out    = (const float*)d_in[11];

  float* out      = (float*)d_out;                 // 256*2048
  float* conv_out = out + 524288;                  // 256*8192*4
  float* ssm_out  = out + 8912896;                 // 256*8192*16

  float* ws   = (float*)d_ws;
  float* xz   = ws;                // 256*16384 = 4,194,304 (reused as split-K partials later)
  float* xcw  = ws + 4194304;      // 256*8192
  float* x_db = ws + 6291456;      // 256*160
  float* dtv  = ws + 6332416;      // 256*8192
  float* yv   = ws + 8429568;      // 256*8192
  float* partials = xz;            // 8*524288 fits exactly in xz's slot

  // 1) xz = x @ W_in.T        M=256 N=16384 K=2048  (512 blocks = 2/CU)
  gemm_bt<0><<<dim3(256, 2, 1), 256, 0, stream>>>(x, W_in, xz, nullptr, 2048, 2048, 16384, 32, 0, 0);
  // 2) conv shift + silu -> conv_out, xc
  conv_step<<<8192, 256, 0, stream>>>(xz, conv_in, conv_w, conv_b, conv_out, xcw);
  // 3) x_db = xc @ W_xproj.T  M=256 N=160 K=8192 (split-K atomics)
  zero_kernel<<<160, 256, 0, stream>>>(x_db);
  gemm_xdb<<<dim3(10, 16), 256, 0, stream>>>(xcw, W_xproj, x_db);
  // 4) dt = softplus(x_db[:, :128] @ W_dt.T + b_dt)   M=256 N=8192 K=128
  gemm_bt<1><<<dim3(128, 2, 1), 256, 0, stream>>>(x_db, W_dt, dtv, b_dt, 160, 128, 8192, 2, 0, 0);
  // 5) SSM update -> ssm_out, y
  ssm_step<<<32768, 256, 0, stream>>>(ssm_in, x_db, dtv, xcw, xz, A_log, D_param, ssm_out, yv);
  // 6) out partials = y @ W_out.T  M=256 N=2048 K=8192, split-K=8 (512 blocks = 2/CU)
  gemm_bt<0><<<dim3(32, 2, 8), 256, 0, stream>>>(yv, W_out, partials, nullptr, 8192, 8192, 2048, 16, 1024, 524288);
  // 7) reduce
  reduce8<<<512, 256, 0, stream>>>(partials, out);
}